// Round 11
// baseline (242.853 us; speedup 1.0000x reference)
//
#include <hip/hip_runtime.h>
#include <hip/hip_fp16.h>

#define NFEAT 128
#define NCLS  64
#define CPB   192      // destination cols per bucket (col_local in bits 17..24)
#define SCAP  3600     // fixed bucket capacity (mean 3072, sigma 55 -> 9.5 sigma)
#define NBMAX 544
#define PCHUNK 8192

typedef _Float16 f16;
typedef __attribute__((ext_vector_type(8))) _Float16 f16x8;
typedef __attribute__((ext_vector_type(4))) float f32x4;

// ---------------- P1 (fat kernel, 512 thr): partition ∥ projection ----------------
// Partition blocks counting-sort their 8K-edge chunk in LDS, then stream each
// bucket-run out CONTIGUOUSLY (full-line writes; kills round-10's write amp).
// Projection blocks: 8 waves x 16 nodes of MFMA x@W^T (u0 unscaled fp16).
__global__ __launch_bounds__(512) void fat_k(const float* __restrict__ x,
                                             const float* __restrict__ W,
                                             const int* __restrict__ row,
                                             const int* __restrict__ col, int E,
                                             int* __restrict__ bcursor,
                                             int* __restrict__ ebuf,
                                             f16* __restrict__ u0,
                                             int n, int NB, int PB) {
    __shared__ union {
        struct {
            int sorted[PCHUNK];    // 32KB: chunk entries in bucket-sorted order
            int hist[NBMAX];
            int sps[NBMAX + 1];    // exclusive prefix (chunk-local)
            int cur[NBMAX];
            int gbase[NBMAX];      // this chunk's reserved base within each bucket
            int sc[512];
        } p;
        __align__(16) f16 zbuf[8][16][64];
    } sh;
    int t = threadIdx.x;

    if ((int)blockIdx.x < PB) {
        // ---- partition path ----
        int start = blockIdx.x * PCHUNK;
        int end   = min(start + PCHUNK, E);
        int cnt_c = end - start;
        for (int i = t; i < NB; i += 512) sh.p.hist[i] = 0;
        __syncthreads();
        for (int k = t; k < cnt_c; k += 512)
            atomicAdd(&sh.p.hist[col[start + k] / CPB], 1);
        __syncthreads();
        // pair-scan: thread t owns hist[2t], hist[2t+1] (covers NBMAX=544)
        int i0 = 2 * t, i1 = 2 * t + 1;
        int a0 = (i0 < NB) ? sh.p.hist[i0] : 0;
        int a1 = (i1 < NB) ? sh.p.hist[i1] : 0;
        sh.p.sc[t] = a0 + a1;
        for (int off = 1; off < 512; off <<= 1) {
            __syncthreads();
            int a = (t >= off) ? sh.p.sc[t - off] : 0;
            __syncthreads();
            sh.p.sc[t] += a;
        }
        __syncthreads();
        int excl = sh.p.sc[t] - a0 - a1;
        if (i0 <= NB) sh.p.sps[i0] = excl;
        if (i1 <= NB) sh.p.sps[i1] = excl + a0;
        if (t == 511) sh.p.sps[NB] = sh.p.sc[511];   // total (idempotent w/ i1==NB case)
        __syncthreads();
        for (int i = t; i < NB; i += 512) {
            int hv = sh.p.hist[i];
            sh.p.gbase[i] = hv ? atomicAdd(&bcursor[i], hv) : 0;
            sh.p.cur[i]   = sh.p.sps[i];
        }
        __syncthreads();
        for (int k = t; k < cnt_c; k += 512) {           // LDS scatter (sorted order)
            int c = col[start + k], b = c / CPB, cl = c - b * CPB;
            int lpos = atomicAdd(&sh.p.cur[b], 1);
            sh.p.sorted[lpos] = row[start + k] | (cl << 17);   // row<2^17, cl<2^8
        }
        __syncthreads();
        for (int k = t; k < cnt_c; k += 512) {           // contiguous run write-out
            int lo = 0, hi = NB;                          // find b: sps[b]<=k<sps[b+1]
            while (hi - lo > 1) {
                int mid = (lo + hi) >> 1;
                if (sh.p.sps[mid] <= k) lo = mid; else hi = mid;
            }
            int off = sh.p.gbase[lo] + (k - sh.p.sps[lo]);
            if (off < SCAP)                               // ~9.5 sigma: never in practice
                ebuf[lo * SCAP + off] = sh.p.sorted[k];
        }
        return;
    }

    // ---- projection path: 8 waves x 16 nodes ----
    int w = t >> 6, l = t & 63;
    int lr = l & 15;   // A-row / B-col within 16
    int lk = l >> 4;   // k-group: k-offset lk*8

    f16x8 bfrag[4][4];
#pragma unroll
    for (int ct = 0; ct < 4; ++ct)
#pragma unroll
        for (int m = 0; m < 4; ++m) {
            const float* wp = &W[(size_t)(ct * 16 + lr) * NFEAT + m * 32 + lk * 8];
            float4 w0 = *reinterpret_cast<const float4*>(wp);
            float4 w1 = *reinterpret_cast<const float4*>(wp + 4);
            f16x8 bb;
            bb[0] = (f16)w0.x; bb[1] = (f16)w0.y; bb[2] = (f16)w0.z; bb[3] = (f16)w0.w;
            bb[4] = (f16)w1.x; bb[5] = (f16)w1.y; bb[6] = (f16)w1.z; bb[7] = (f16)w1.w;
            bfrag[ct][m] = bb;
        }

    int nb = (blockIdx.x - PB) * 128 + w * 16;
    int arow = nb + lr;
    bool aok = arow < n;
    const float* xp = &x[(size_t)(aok ? arow : 0) * NFEAT + lk * 8];

    f32x4 acc[4];
#pragma unroll
    for (int ct = 0; ct < 4; ++ct) acc[ct] = (f32x4){0.f, 0.f, 0.f, 0.f};

#pragma unroll
    for (int m = 0; m < 4; ++m) {
        float4 x0 = make_float4(0.f, 0.f, 0.f, 0.f);
        float4 x1 = make_float4(0.f, 0.f, 0.f, 0.f);
        if (aok) {
            x0 = *reinterpret_cast<const float4*>(xp + m * 32);
            x1 = *reinterpret_cast<const float4*>(xp + m * 32 + 4);
        }
        f16x8 a;
        a[0] = (f16)x0.x; a[1] = (f16)x0.y; a[2] = (f16)x0.z; a[3] = (f16)x0.w;
        a[4] = (f16)x1.x; a[5] = (f16)x1.y; a[6] = (f16)x1.z; a[7] = (f16)x1.w;
#pragma unroll
        for (int ct = 0; ct < 4; ++ct)
            acc[ct] = __builtin_amdgcn_mfma_f32_16x16x32_f16(a, bfrag[ct][m], acc[ct], 0, 0, 0);
    }

#pragma unroll
    for (int ct = 0; ct < 4; ++ct)
#pragma unroll
        for (int r = 0; r < 4; ++r)
            sh.zbuf[w][lk * 4 + r][ct * 16 + lr] = (f16)acc[ct][r];
    __builtin_amdgcn_s_waitcnt(0);   // same-wave LDS RAW (no barrier needed)

    const uint4* zb = reinterpret_cast<const uint4*>(&sh.zbuf[w][0][0]);
    uint4 v0 = zb[l * 2], v1 = zb[l * 2 + 1];
    int node = nb + (l >> 2);
    if (node < n) {
        uint4* op = reinterpret_cast<uint4*>(&u0[(size_t)node * NCLS + (l & 3) * 16]);
        op[0] = v0; op[1] = v1;
    }
}

// ---------------- P2 (512 thr): per-bucket counting sort -> CSR + dinv + pc + z-scale
__global__ __launch_bounds__(512) void sort_k(const int* __restrict__ ebuf,
                                              const int* __restrict__ bcursor,
                                              const f16* __restrict__ u0,
                                              f16* __restrict__ z0,
                                              float* __restrict__ dinv,
                                              int2* __restrict__ pc,
                                              int* __restrict__ csr, int N) {
    __shared__ int sld[SCAP];
    __shared__ int h[CPB];
    __shared__ int cur[CPB];
    __shared__ int sc[512];
    __shared__ float ds[CPB];
    int b = blockIdx.x, t = threadIdx.x;
    int base = b * SCAP;
    int cntb = min(bcursor[b], SCAP);
    if (t < CPB) h[t] = 0;
    for (int j = t; j < cntb; j += 512) sld[j] = ebuf[base + j];
    __syncthreads();
    for (int j = t; j < cntb; j += 512)
        atomicAdd(&h[sld[j] >> 17], 1);
    __syncthreads();
    int v = (t < CPB) ? h[t] : 0;
    sc[t] = v;
    for (int off = 1; off < 256; off <<= 1) {   // scan first 256 covers CPB=192
        __syncthreads();
        int a = (t >= off && t < 256) ? sc[t - off] : 0;
        __syncthreads();
        if (t < 256) sc[t] += a;
    }
    __syncthreads();
    if (t < CPB) {
        int c = b * CPB + t;
        int p = base + sc[t] - v;          // absolute csr position (fixed-slot layout)
        cur[t] = p;
        float d = rsqrtf((float)(v + 1));  // +1: self-loop
        ds[t] = d;
        if (c < N) {
            pc[c] = make_int2(p, v);
            dinv[c] = d;
        }
    }
    __syncthreads();
    for (int j = t; j < cntb; j += 512) {
        int e = sld[j];
        int pos = atomicAdd(&cur[e >> 17], 1);
        csr[pos] = e & 0x1FFFF;
    }
    // z-scale epilogue: z0 = ds ⊙ u0 for this bucket's nodes (coalesced, ds in LDS)
    int nodes = min(CPB, N - b * CPB);
    if (nodes > 0) {
        const uint4* up = reinterpret_cast<const uint4*>(u0 + (size_t)b * CPB * NCLS);
        uint4* zp = reinterpret_cast<uint4*>(z0 + (size_t)b * CPB * NCLS);
        int tot = nodes * 8;               // 8 uint4 per 64-half row
        for (int i = t; i < tot; i += 512) {
            float d = ds[i >> 3];
            uint4 vv = up[i];
            __half2* hv = reinterpret_cast<__half2*>(&vv);
#pragma unroll
            for (int k = 0; k < 4; ++k) {
                float2 f = __half22float2(hv[k]);
                hv[k] = __floats2half2_rn(f.x * d, f.y * d);
            }
            zp[i] = vv;
        }
    }
}

// ---------------- P3: SpMM hop, deep gather issue (self hoisted to front) ----------
template <int FINAL>
__global__ __launch_bounds__(256) void spmm_k(const __half* __restrict__ zin,
                                              void* __restrict__ outp,
                                              const int2* __restrict__ pc,
                                              const float* __restrict__ dinv,
                                              const int* __restrict__ csr,
                                              const float* __restrict__ bias, int n) {
    int t = threadIdx.x;
    int lane = t & 63;
    int wid  = blockIdx.x * 4 + (t >> 6);
    wid = __builtin_amdgcn_readfirstlane(wid);
    if (wid >= n) return;

    int sub = lane >> 3;        // edge slot 0..7
    int cg  = (lane & 7) * 8;   // class octet base (halves)

#define GATHER(r) (*reinterpret_cast<const uint4*>(&zin[(size_t)(r) * NCLS + cg]))

    int2 se = pc[wid];
    uint4 sv = GATHER(wid);     // self term: issue first, consumed after reduce
    float d = dinv[wid];
    int s = se.x, e = s + se.y;

    float a[8];
#pragma unroll
    for (int k = 0; k < 8; ++k) a[k] = 0.f;

#define ACCUM(u)                                                            \
    {                                                                       \
        __half2 t0 = *reinterpret_cast<const __half2*>(&u.x);               \
        __half2 t1 = *reinterpret_cast<const __half2*>(&u.y);               \
        __half2 t2 = *reinterpret_cast<const __half2*>(&u.z);               \
        __half2 t3 = *reinterpret_cast<const __half2*>(&u.w);               \
        float2 f0 = __half22float2(t0), f1 = __half22float2(t1);            \
        float2 f2 = __half22float2(t2), f3 = __half22float2(t3);            \
        a[0] += f0.x; a[1] += f0.y; a[2] += f1.x; a[3] += f1.y;             \
        a[4] += f2.x; a[5] += f2.y; a[6] += f3.x; a[7] += f3.y;             \
    }

    int j = s;
    while (e - j >= 32) {                      // rare (deg>=32): 4 in flight
        int r0 = csr[j + sub],      r1 = csr[j + 8 + sub];
        int r2 = csr[j + 16 + sub], r3 = csr[j + 24 + sub];
        uint4 g0 = GATHER(r0), g1 = GATHER(r1), g2 = GATHER(r2), g3 = GATHER(r3);
        ACCUM(g0); ACCUM(g1); ACCUM(g2); ACCUM(g3);
        j += 32;
    }
    // tail: 0..31 edges. f full batches (scalar guard), then partial (lane guard).
    int f = (e - j) >> 3;                      // 0..3
    uint4 g0, g1, g2, g3;
    bool p = (j + f * 8 + sub) < e;
    if (f > 0) { int r = csr[j + sub];           g0 = GATHER(r); }
    if (f > 1) { int r = csr[j + 8 + sub];       g1 = GATHER(r); }
    if (f > 2) { int r = csr[j + 16 + sub];      g2 = GATHER(r); }
    if (p)     { int r = csr[j + f * 8 + sub];   g3 = GATHER(r); }
    if (f > 0) ACCUM(g0);
    if (f > 1) ACCUM(g1);
    if (f > 2) ACCUM(g2);
    if (p)     ACCUM(g3);

#pragma unroll
    for (int m = 8; m <= 32; m <<= 1)
#pragma unroll
        for (int k = 0; k < 8; ++k)
            a[k] += __shfl_xor(a[k], m, 64);

    ACCUM(sv);                                 // self term (counted once post-reduce)
#undef GATHER
#undef ACCUM

    if (FINAL) {
        float* out = (float*)outp;
        float4 b0 = *reinterpret_cast<const float4*>(&bias[cg]);
        float4 b1 = *reinterpret_cast<const float4*>(&bias[cg + 4]);
        if (sub == 0) {
            float4 o0, o1;
            o0.x = fmaf(d, a[0], b0.x); o0.y = fmaf(d, a[1], b0.y);
            o0.z = fmaf(d, a[2], b0.z); o0.w = fmaf(d, a[3], b0.w);
            o1.x = fmaf(d, a[4], b1.x); o1.y = fmaf(d, a[5], b1.y);
            o1.z = fmaf(d, a[6], b1.z); o1.w = fmaf(d, a[7], b1.w);
            *reinterpret_cast<float4*>(&out[(size_t)wid * NCLS + cg])     = o0;
            *reinterpret_cast<float4*>(&out[(size_t)wid * NCLS + cg + 4]) = o1;
        }
    } else {
        __half* zo = (__half*)outp;
        float d2 = d * d;
        if (sub == 0) {
            __half2 h0 = __floats2half2_rn(d2 * a[0], d2 * a[1]);
            __half2 h1 = __floats2half2_rn(d2 * a[2], d2 * a[3]);
            __half2 h2 = __floats2half2_rn(d2 * a[4], d2 * a[5]);
            __half2 h3 = __floats2half2_rn(d2 * a[6], d2 * a[7]);
            uint4 pk;
            pk.x = *reinterpret_cast<unsigned int*>(&h0);
            pk.y = *reinterpret_cast<unsigned int*>(&h1);
            pk.z = *reinterpret_cast<unsigned int*>(&h2);
            pk.w = *reinterpret_cast<unsigned int*>(&h3);
            *reinterpret_cast<uint4*>(&zo[(size_t)wid * NCLS + cg]) = pk;
        }
    }
}

// ---------------- launch ----------------
extern "C" void kernel_launch(void* const* d_in, const int* in_sizes, int n_in,
                              void* d_out, int out_size, void* d_ws, size_t ws_size,
                              hipStream_t stream) {
    const float* x  = (const float*)d_in[0];
    const int*   ei = (const int*)d_in[1];
    const float* W  = (const float*)d_in[2];
    const float* b  = (const float*)d_in[3];

    const int N = in_sizes[0] / NFEAT;   // 100000
    const int E = in_sizes[1] / 2;       // 1600000
    const int* row = ei;
    const int* col = ei + E;
    const int NB = (N + CPB - 1) / CPB;  // 521
    if (NB > NBMAX) return;

    const int PB    = (E + PCHUNK - 1) / PCHUNK;   // 196 partition blocks
    const int PROJB = (N + 127) / 128;             // 782 projection blocks (8 waves)

    // workspace layout (z1 reuses u0's storage: u0 dead after sort_k)
    const size_t SLOTS = (size_t)NB * SCAP;          // 1,875,600
    f16*   u0      = (f16*)d_ws;                     // N*64 halves (-> z1 later)
    f16*   z0      = u0 + (size_t)N * NCLS;          // N*64 halves
    int*   ebuf    = (int*)(z0 + (size_t)N * NCLS);  // SLOTS
    int*   csr     = ebuf + SLOTS;                   // SLOTS
    float* dinv    = (float*)(csr + SLOTS);          // N
    int2*  pc      = (int2*)(dinv + N);              // N int2
    int*   bcursor = (int*)(pc + N);                 // NB

    size_t needed = (size_t)N * NCLS * 2 * 2
                  + (SLOTS * 2 + (size_t)N * 3 + (size_t)NB) * 4;
    if (ws_size < needed) return;

    hipMemsetAsync(bcursor, 0, (size_t)NB * 4, stream);
    fat_k<<<PB + PROJB, 512, 0, stream>>>(x, W, row, col, E, bcursor, ebuf, u0, N, NB, PB);
    sort_k<<<NB, 512, 0, stream>>>(ebuf, bcursor, u0, z0, dinv, pc, csr, N);

    f16* z1 = u0;   // reuse
    spmm_k<0><<<(N + 3) / 4, 256, 0, stream>>>((const __half*)z0, (void*)z1, pc, dinv, csr, b, N);
    spmm_k<1><<<(N + 3) / 4, 256, 0, stream>>>((const __half*)z1, d_out,     pc, dinv, csr, b, N);
}

// Round 12
// 238.819 us; speedup vs baseline: 1.0169x; 1.0169x over previous
//
#include <hip/hip_runtime.h>
#include <hip/hip_fp16.h>

#define NFEAT 128
#define NCLS  64
#define CPB   192      // destination cols per bucket (col_local in bits 17..24)
#define SCAP  3600     // fixed bucket capacity (mean 3072, sigma 55 -> 9.5 sigma)
#define NBMAX 544
#define PCHUNK 8192

typedef _Float16 f16;
typedef __attribute__((ext_vector_type(8))) _Float16 f16x8;
typedef __attribute__((ext_vector_type(4))) float f32x4;

// ---------------- P1 (fat kernel, 512 thr): partition ∥ projection ----------------
// Partition: round-9 direct scatter (shortest measured serial chain; write amp is
// free because the kernel is latency-bound, not BW-bound). Union LDS = 16KB.
__global__ __launch_bounds__(512) void fat_k(const float* __restrict__ x,
                                             const float* __restrict__ W,
                                             const int* __restrict__ row,
                                             const int* __restrict__ col, int E,
                                             int* __restrict__ bcursor,
                                             int* __restrict__ ebuf,
                                             f16* __restrict__ u0,
                                             int n, int NB, int PB) {
    __shared__ union {
        struct { int h[NBMAX]; int cur[NBMAX]; } p;
        __align__(16) f16 zbuf[8][16][64];
    } sh;
    int t = threadIdx.x;

    if ((int)blockIdx.x < PB) {
        // ---- partition path (col read twice; 2nd pass L2-hot) ----
        int start = blockIdx.x * PCHUNK;
        int end   = min(start + PCHUNK, E);
        for (int i = t; i < NB; i += 512) sh.p.h[i] = 0;
        __syncthreads();
        for (int e = start + t; e < end; e += 512)
            atomicAdd(&sh.p.h[col[e] / CPB], 1);
        __syncthreads();
        for (int i = t; i < NB; i += 512)
            sh.p.cur[i] = i * SCAP + (sh.p.h[i] ? atomicAdd(&bcursor[i], sh.p.h[i]) : 0);
        __syncthreads();
        for (int e = start + t; e < end; e += 512) {
            int c = col[e], b = c / CPB, cl = c - b * CPB;
            int pos = atomicAdd(&sh.p.cur[b], 1);
            if (pos < (b + 1) * SCAP)                       // ~9.5 sigma: never in practice
                ebuf[pos] = row[e] | (cl << 17);            // row < 2^17, cl < 2^8
        }
        return;
    }

    // ---- projection path: 8 waves x 16 nodes, u0 = fp16(x @ W^T) unscaled ----
    int w = t >> 6, l = t & 63;
    int lr = l & 15;   // A-row / B-col within 16
    int lk = l >> 4;   // k-group: k-offset lk*8

    f16x8 bfrag[4][4];
#pragma unroll
    for (int ct = 0; ct < 4; ++ct)
#pragma unroll
        for (int m = 0; m < 4; ++m) {
            const float* wp = &W[(size_t)(ct * 16 + lr) * NFEAT + m * 32 + lk * 8];
            float4 w0 = *reinterpret_cast<const float4*>(wp);
            float4 w1 = *reinterpret_cast<const float4*>(wp + 4);
            f16x8 bb;
            bb[0] = (f16)w0.x; bb[1] = (f16)w0.y; bb[2] = (f16)w0.z; bb[3] = (f16)w0.w;
            bb[4] = (f16)w1.x; bb[5] = (f16)w1.y; bb[6] = (f16)w1.z; bb[7] = (f16)w1.w;
            bfrag[ct][m] = bb;
        }

    int nb = (blockIdx.x - PB) * 128 + w * 16;
    int arow = nb + lr;
    bool aok = arow < n;
    const float* xp = &x[(size_t)(aok ? arow : 0) * NFEAT + lk * 8];

    f32x4 acc[4];
#pragma unroll
    for (int ct = 0; ct < 4; ++ct) acc[ct] = (f32x4){0.f, 0.f, 0.f, 0.f};

#pragma unroll
    for (int m = 0; m < 4; ++m) {
        float4 x0 = make_float4(0.f, 0.f, 0.f, 0.f);
        float4 x1 = make_float4(0.f, 0.f, 0.f, 0.f);
        if (aok) {
            x0 = *reinterpret_cast<const float4*>(xp + m * 32);
            x1 = *reinterpret_cast<const float4*>(xp + m * 32 + 4);
        }
        f16x8 a;
        a[0] = (f16)x0.x; a[1] = (f16)x0.y; a[2] = (f16)x0.z; a[3] = (f16)x0.w;
        a[4] = (f16)x1.x; a[5] = (f16)x1.y; a[6] = (f16)x1.z; a[7] = (f16)x1.w;
#pragma unroll
        for (int ct = 0; ct < 4; ++ct)
            acc[ct] = __builtin_amdgcn_mfma_f32_16x16x32_f16(a, bfrag[ct][m], acc[ct], 0, 0, 0);
    }

#pragma unroll
    for (int ct = 0; ct < 4; ++ct)
#pragma unroll
        for (int r = 0; r < 4; ++r)
            sh.zbuf[w][lk * 4 + r][ct * 16 + lr] = (f16)acc[ct][r];
    __builtin_amdgcn_s_waitcnt(0);   // same-wave LDS RAW (no barrier needed)

    const uint4* zb = reinterpret_cast<const uint4*>(&sh.zbuf[w][0][0]);
    uint4 v0 = zb[l * 2], v1 = zb[l * 2 + 1];
    int node = nb + (l >> 2);
    if (node < n) {
        uint4* op = reinterpret_cast<uint4*>(&u0[(size_t)node * NCLS + (l & 3) * 16]);
        op[0] = v0; op[1] = v1;
    }
}

// ---------------- P2 (512 thr, 2.5KB LDS): degrees -> pc/dinv + z-scale ------------
// Streams ebuf directly (no LDS staging). Epilogue: z0 = dinv ⊙ u0 for the block's
// own 192 nodes (their dinv just computed, held in LDS).
__global__ __launch_bounds__(512) void degscale_k(const int* __restrict__ ebuf,
                                                  const int* __restrict__ bcursor,
                                                  const f16* __restrict__ u0,
                                                  f16* __restrict__ z0,
                                                  float* __restrict__ dinv,
                                                  int2* __restrict__ pc, int N) {
    __shared__ int h[CPB];
    __shared__ int sc[256];
    __shared__ float ds[CPB];
    int b = blockIdx.x, t = threadIdx.x;
    if (t < CPB) h[t] = 0;
    __syncthreads();
    int base = b * SCAP;
    int cntb = min(bcursor[b], SCAP);
    for (int j = t; j < cntb; j += 512)
        atomicAdd(&h[ebuf[base + j] >> 17], 1);
    __syncthreads();
    int v = (t < CPB) ? h[t] : 0;
    if (t < 256) sc[t] = v;
    for (int off = 1; off < 256; off <<= 1) {
        __syncthreads();
        int a = (t >= off && t < 256) ? sc[t - off] : 0;
        __syncthreads();
        if (t < 256) sc[t] += a;
    }
    __syncthreads();
    if (t < CPB) {
        int c = b * CPB + t;
        float d = rsqrtf((float)(v + 1));   // +1: self-loop
        ds[t] = d;
        if (c < N) {
            pc[c] = make_int2(base + sc[t] - v, v);   // absolute csr start, count
            dinv[c] = d;
        }
    }
    __syncthreads();
    int nodes = min(CPB, N - b * CPB);
    if (nodes > 0) {
        const uint4* up = reinterpret_cast<const uint4*>(u0 + (size_t)b * CPB * NCLS);
        uint4* zp = reinterpret_cast<uint4*>(z0 + (size_t)b * CPB * NCLS);
        int tot = nodes * 8;               // 8 uint4 per 64-half row
        for (int i = t; i < tot; i += 512) {
            float d = ds[i >> 3];
            uint4 vv = up[i];
            __half2* hv = reinterpret_cast<__half2*>(&vv);
#pragma unroll
            for (int k = 0; k < 4; ++k) {
                float2 f = __half22float2(hv[k]);
                hv[k] = __floats2half2_rn(f.x * d, f.y * d);
            }
            zp[i] = vv;
        }
    }
}

// ---------------- P3 (512 thr, 768B LDS): scatter ebuf -> per-node CSR -------------
// cur comes straight from pc (no re-hist/scan); pure stream + LDS atomic + store.
__global__ __launch_bounds__(512) void sort_k(const int* __restrict__ ebuf,
                                              const int* __restrict__ bcursor,
                                              const int2* __restrict__ pc,
                                              int* __restrict__ csr, int N) {
    __shared__ int cur[CPB];
    int b = blockIdx.x, t = threadIdx.x;
    if (t < CPB) {
        int c = b * CPB + t;
        cur[t] = (c < N) ? pc[c].x : 0;
    }
    __syncthreads();
    int base = b * SCAP;
    int cntb = min(bcursor[b], SCAP);
    for (int j = t; j < cntb; j += 512) {
        int e = ebuf[base + j];
        int pos = atomicAdd(&cur[e >> 17], 1);
        csr[pos] = e & 0x1FFFF;
    }
}

// ---------------- P4: SpMM hop, deep gather issue (self hoisted to front) ----------
template <int FINAL>
__global__ __launch_bounds__(256) void spmm_k(const __half* __restrict__ zin,
                                              void* __restrict__ outp,
                                              const int2* __restrict__ pc,
                                              const float* __restrict__ dinv,
                                              const int* __restrict__ csr,
                                              const float* __restrict__ bias, int n) {
    int t = threadIdx.x;
    int lane = t & 63;
    int wid  = blockIdx.x * 4 + (t >> 6);
    wid = __builtin_amdgcn_readfirstlane(wid);
    if (wid >= n) return;

    int sub = lane >> 3;        // edge slot 0..7
    int cg  = (lane & 7) * 8;   // class octet base (halves)

#define GATHER(r) (*reinterpret_cast<const uint4*>(&zin[(size_t)(r) * NCLS + cg]))

    int2 se = pc[wid];
    uint4 sv = GATHER(wid);     // self term: issue first, consumed after reduce
    float d = dinv[wid];
    int s = se.x, e = s + se.y;

    float a[8];
#pragma unroll
    for (int k = 0; k < 8; ++k) a[k] = 0.f;

#define ACCUM(u)                                                            \
    {                                                                       \
        __half2 t0 = *reinterpret_cast<const __half2*>(&u.x);               \
        __half2 t1 = *reinterpret_cast<const __half2*>(&u.y);               \
        __half2 t2 = *reinterpret_cast<const __half2*>(&u.z);               \
        __half2 t3 = *reinterpret_cast<const __half2*>(&u.w);               \
        float2 f0 = __half22float2(t0), f1 = __half22float2(t1);            \
        float2 f2 = __half22float2(t2), f3 = __half22float2(t3);            \
        a[0] += f0.x; a[1] += f0.y; a[2] += f1.x; a[3] += f1.y;             \
        a[4] += f2.x; a[5] += f2.y; a[6] += f3.x; a[7] += f3.y;             \
    }

    int j = s;
    while (e - j >= 32) {                      // rare (deg>=32): 4 in flight
        int r0 = csr[j + sub],      r1 = csr[j + 8 + sub];
        int r2 = csr[j + 16 + sub], r3 = csr[j + 24 + sub];
        uint4 g0 = GATHER(r0), g1 = GATHER(r1), g2 = GATHER(r2), g3 = GATHER(r3);
        ACCUM(g0); ACCUM(g1); ACCUM(g2); ACCUM(g3);
        j += 32;
    }
    // tail: 0..31 edges. f full batches (scalar guard), then partial (lane guard).
    int f = (e - j) >> 3;                      // 0..3
    uint4 g0, g1, g2, g3;
    bool p = (j + f * 8 + sub) < e;
    if (f > 0) { int r = csr[j + sub];           g0 = GATHER(r); }
    if (f > 1) { int r = csr[j + 8 + sub];       g1 = GATHER(r); }
    if (f > 2) { int r = csr[j + 16 + sub];      g2 = GATHER(r); }
    if (p)     { int r = csr[j + f * 8 + sub];   g3 = GATHER(r); }
    if (f > 0) ACCUM(g0);
    if (f > 1) ACCUM(g1);
    if (f > 2) ACCUM(g2);
    if (p)     ACCUM(g3);

#pragma unroll
    for (int m = 8; m <= 32; m <<= 1)
#pragma unroll
        for (int k = 0; k < 8; ++k)
            a[k] += __shfl_xor(a[k], m, 64);

    ACCUM(sv);                                 // self term (counted once post-reduce)
#undef GATHER
#undef ACCUM

    if (FINAL) {
        float* out = (float*)outp;
        float4 b0 = *reinterpret_cast<const float4*>(&bias[cg]);
        float4 b1 = *reinterpret_cast<const float4*>(&bias[cg + 4]);
        if (sub == 0) {
            float4 o0, o1;
            o0.x = fmaf(d, a[0], b0.x); o0.y = fmaf(d, a[1], b0.y);
            o0.z = fmaf(d, a[2], b0.z); o0.w = fmaf(d, a[3], b0.w);
            o1.x = fmaf(d, a[4], b1.x); o1.y = fmaf(d, a[5], b1.y);
            o1.z = fmaf(d, a[6], b1.z); o1.w = fmaf(d, a[7], b1.w);
            *reinterpret_cast<float4*>(&out[(size_t)wid * NCLS + cg])     = o0;
            *reinterpret_cast<float4*>(&out[(size_t)wid * NCLS + cg + 4]) = o1;
        }
    } else {
        __half* zo = (__half*)outp;
        float d2 = d * d;
        if (sub == 0) {
            __half2 h0 = __floats2half2_rn(d2 * a[0], d2 * a[1]);
            __half2 h1 = __floats2half2_rn(d2 * a[2], d2 * a[3]);
            __half2 h2 = __floats2half2_rn(d2 * a[4], d2 * a[5]);
            __half2 h3 = __floats2half2_rn(d2 * a[6], d2 * a[7]);
            uint4 pk;
            pk.x = *reinterpret_cast<unsigned int*>(&h0);
            pk.y = *reinterpret_cast<unsigned int*>(&h1);
            pk.z = *reinterpret_cast<unsigned int*>(&h2);
            pk.w = *reinterpret_cast<unsigned int*>(&h3);
            *reinterpret_cast<uint4*>(&zo[(size_t)wid * NCLS + cg]) = pk;
        }
    }
}

// ---------------- launch ----------------
extern "C" void kernel_launch(void* const* d_in, const int* in_sizes, int n_in,
                              void* d_out, int out_size, void* d_ws, size_t ws_size,
                              hipStream_t stream) {
    const float* x  = (const float*)d_in[0];
    const int*   ei = (const int*)d_in[1];
    const float* W  = (const float*)d_in[2];
    const float* b  = (const float*)d_in[3];

    const int N = in_sizes[0] / NFEAT;   // 100000
    const int E = in_sizes[1] / 2;       // 1600000
    const int* row = ei;
    const int* col = ei + E;
    const int NB = (N + CPB - 1) / CPB;  // 521
    if (NB > NBMAX) return;

    const int PB    = (E + PCHUNK - 1) / PCHUNK;   // 196 partition blocks
    const int PROJB = (N + 127) / 128;             // 782 projection blocks (8 waves)

    // workspace layout (z1 reuses u0's storage: u0 dead after degscale_k)
    const size_t SLOTS = (size_t)NB * SCAP;          // 1,875,600
    f16*   u0      = (f16*)d_ws;                     // N*64 halves (-> z1 later)
    f16*   z0      = u0 + (size_t)N * NCLS;          // N*64 halves
    int*   ebuf    = (int*)(z0 + (size_t)N * NCLS);  // SLOTS
    int*   csr     = ebuf + SLOTS;                   // SLOTS
    float* dinv    = (float*)(csr + SLOTS);          // N
    int2*  pc      = (int2*)(dinv + N);              // N int2
    int*   bcursor = (int*)(pc + N);                 // NB

    size_t needed = (size_t)N * NCLS * 2 * 2
                  + (SLOTS * 2 + (size_t)N * 3 + (size_t)NB) * 4;
    if (ws_size < needed) return;

    hipMemsetAsync(bcursor, 0, (size_t)NB * 4, stream);
    fat_k<<<PB + PROJB, 512, 0, stream>>>(x, W, row, col, E, bcursor, ebuf, u0, N, NB, PB);
    degscale_k<<<NB, 512, 0, stream>>>(ebuf, bcursor, u0, z0, dinv, pc, N);
    sort_k<<<NB, 512, 0, stream>>>(ebuf, bcursor, pc, csr, N);

    f16* z1 = u0;   // reuse
    spmm_k<0><<<(N + 3) / 4, 256, 0, stream>>>((const __half*)z0, (void*)z1, pc, dinv, csr, b, N);
    spmm_k<1><<<(N + 3) / 4, 256, 0, stream>>>((const __half*)z1, d_out,     pc, dinv, csr, b, N);
}